// Round 6
// baseline (1521.811 us; speedup 1.0000x reference)
//
#include <hip/hip_runtime.h>
#include <hip/hip_bf16.h>
#include <cstdint>

// EdgeFrontierPolicy: E=400000, G=64, H=256.
// Wave-independent design: W1^T resident in LDS (128KB, frag-packed, ln1_g
// folded), each wave owns a 32-edge tile end-to-end with ZERO barriers after
// the prologue. GEMM1 computed transposed (h1^T = W1g^T x zln^T) so LN output
// feeds MFMA directly from registers; h1^T -> h1 A-frags via shuffles;
// GEMM2 B-frags streamed from L2 with register triple-buffer.
// KEY FIX vs r4/r5: amdgpu_waves_per_eu(2,2) pins the allocator at exactly
// 2 waves/EU (256-VGPR budget). launch_bounds' min-waves form let LLVM's
// occupancy heuristic target 4 waves/EU (128 VGPR) and spill ~GBs to scratch.

typedef __bf16 bf16x8 __attribute__((ext_vector_type(8)));
typedef float  f32x4  __attribute__((ext_vector_type(4)));

typedef __attribute__((address_space(1))) const char gas_char;
typedef __attribute__((address_space(3))) char las_char;

__device__ __forceinline__ float gelu_f(float x) {
  float x2 = x * x;
  float t1 = __builtin_fmaf(0.1029444f, x2, 2.3022078f);
  float a  = x * t1;
  float e;
  asm("v_exp_f32 %0, %1" : "=v"(e) : "v"(a));
  float r;
  asm("v_rcp_f32 %0, %1" : "=v"(r) : "v"(e + 1.0f));
  return x - x * r;
}

__device__ __forceinline__ bf16x8 as_frag(uint4 u) {
  union { uint4 u; bf16x8 f; } c; c.u = u; return c.f;
}
__device__ __forceinline__ unsigned pk2(float a, float b) {
  union { __bf16 h[2]; unsigned u; } c;
  c.h[0] = (__bf16)a; c.h[1] = (__bf16)b; return c.u;
}

// ---------------------------------------------------------------------------
// Pack W1 (ln1_g folded) / W2 into MFMA frag order, bf16.
// out[((kt*16+nt)*64 + l)*8 + i] = W[32kt + 8*(l>>4)+i][16nt + (l&15)]
// (B-frag pack of W == A-frag pack of W^T: reused for both GEMMs.)
__global__ void prep_pack(const float* __restrict__ W1, const float* __restrict__ W2,
                          const float* __restrict__ ln1g,
                          __bf16* __restrict__ W1p, __bf16* __restrict__ W2p) {
  int gid = blockIdx.x * blockDim.x + threadIdx.x;   // 16384 threads
  int m  = gid >> 13;
  int b  = (gid >> 6) & 127;
  int l  = gid & 63;
  int kt = b >> 4, nt = b & 15;
  int k0 = kt * 32 + ((l >> 4) << 3);
  int n  = nt * 16 + (l & 15);
  const float* W = m ? W2 : W1;
  bf16x8 v;
#pragma unroll
  for (int i = 0; i < 8; ++i) {
    int k = k0 + i;
    float wv = W[k * 256 + n];
    if (!m) wv *= ln1g[k];
    v[i] = (__bf16)wv;
  }
  __bf16* dst = m ? W2p : W1p;
  *(bf16x8*)(dst + (size_t)(b * 64 + l) * 8) = v;
}

// C0/GW6/GW7 + mask dtype detect.
__global__ void prep_vec(const float* __restrict__ W1, const float* __restrict__ ln1g,
                         const float* __restrict__ ln1b, const float* __restrict__ b1,
                         const unsigned* __restrict__ smask_words,
                         float* __restrict__ C0, float* __restrict__ GW6,
                         float* __restrict__ GW7, int* __restrict__ maskIsByte) {
  __shared__ float red[4][256];
  const int n = threadIdx.x & 255, c = threadIdx.x >> 8;
  const int k0 = c * 64, k1 = (c == 3) ? 258 : k0 + 64;
  float s = 0.f;
#pragma unroll 4
  for (int k = k0; k < k1; ++k) s += ln1b[k] * W1[k * 256 + n];
  red[c][n] = s;
  __syncthreads();
  if (c == 0) {
    C0[n]  = b1[n] + red[0][n] + red[1][n] + red[2][n] + red[3][n];
    GW6[n] = ln1g[256] * W1[256 * 256 + n];
    GW7[n] = ln1g[257] * W1[257 * 256 + n];
  }
  if (threadIdx.x == 0) {
    int big = 0;
    for (int i = 0; i < 64; ++i) { if (smask_words[i] > 1u) big = 1; }
    *maskIsByte = big;
  }
}

// ---------------------------------------------------------------------------
__global__ void
__attribute__((amdgpu_flat_work_group_size(512, 512), amdgpu_waves_per_eu(2, 2)))
edge_kernel(
    const float* __restrict__ tok, const int* __restrict__ ebatch,
    const unsigned char* __restrict__ smaskB,
    const int* __restrict__ eheads, const int* __restrict__ etails,
    const int* __restrict__ curtail,
    const __bf16* __restrict__ W1p, const __bf16* __restrict__ W2p,
    const float* __restrict__ C0v, const float* __restrict__ GW6v,
    const float* __restrict__ GW7v, const float* __restrict__ b2v,
    const float* __restrict__ selwv, const float* __restrict__ selbv,
    const int* __restrict__ maskFlag,
    float* __restrict__ outLogits, float* __restrict__ pooledAcc,
    float* __restrict__ cnts, int E) {
  __shared__ __align__(16) char Wlds[131072];     // W1^T frag-packed, resident
  __shared__ float sC0[256], sW6[256], sW7[256], sSelw[256], sB2[256];

  const int t  = threadIdx.x;
  const int w  = t >> 6, l = t & 63;
  const int lo = l & 15, g = l >> 4;

  // ---- prologue: stage W1^T -> LDS (wave-linear), small vectors -> LDS ----
  {
    const char* Wsrc = (const char*)W1p;
    unsigned woff = __builtin_amdgcn_readfirstlane((unsigned)w * 16384u);
#pragma unroll
    for (int it = 0; it < 16; ++it)
      __builtin_amdgcn_global_load_lds((gas_char*)(Wsrc + woff + it * 1024 + l * 16),
                                       (las_char*)(Wlds + woff + it * 1024), 16, 0, 0);
  }
  if (t < 256) {
    sC0[t] = C0v[t]; sW6[t] = GW6v[t]; sW7[t] = GW7v[t];
    sSelw[t] = selwv[t]; sB2[t] = b2v[t];
  }
  const int   mb    = *maskFlag;
  const float selbr = selbv[0];
  __syncthreads();   // drains global_load_lds; LAST barrier in the kernel

  const int totalTiles = E >> 5;                 // 32 edges per tile
  const int nWaves = gridDim.x * 8;
  const char* W2c = (const char*)W2p;

  for (int tile = blockIdx.x * 8 + w; tile < totalTiles; tile += nWaves) {
    const int base = tile << 5;

    // ---- flags (lanes 0..31, one edge each) ----
    float candf = 0.f, frontf = 0.f; int gid = 0;
    if (l < 32) {
      int ge = base + l;
      gid = ebatch[ge];
      int mv = mb ? (int)smaskB[ge] : ((const int*)smaskB)[ge];
      int cand = (mv == 0);
      int cur  = curtail[gid];
      int fr   = cand && ((eheads[ge] == cur) || (etails[ge] == cur));
      candf = (float)cand; frontf = (float)fr;
    }
    const int g0s = __shfl(gid, 0);
    const bool uniform =
        (__ballot((l < 32) ? (gid == g0s) : 1) == ~0ull);
    {  // counts: boundary lanes add run lengths
      int gp = __shfl(gid, (l == 0) ? 0 : l - 1);
      bool isb = (l < 32) && (l == 0 || gid != gp);
      unsigned long long bm = __ballot(isb);
      if (isb) {
        unsigned long long m2 = bm >> (l + 1);
        int run = m2 ? (int)__ffsll((long long)m2) : (32 - l);
        atomicAdd(&cnts[gid], (float)run);
      }
    }
    // flags to row owners (row a = lo, row b = 16+lo)
    const float ca = __shfl(candf, lo),      fa = __shfl(frontf, lo);
    const float cb = __shfl(candf, 16 + lo), fb = __shfl(frontf, 16 + lo);

    // ---- LayerNorm, fully in-register; produce zln B-frags per row ----
    uint4 zlnA[8], zlnB[8];
    float za0a, za1a, za0b, za1b;
#pragma unroll
    for (int rr = 0; rr < 2; ++rr) {
      const int   edge = base + rr * 16 + lo;
      const float aux0 = rr ? cb : ca, aux1 = rr ? fb : fa;
      const float* rp = tok + (size_t)edge * 256 + (g << 3);
      float4 v[16];
#pragma unroll
      for (int kt = 0; kt < 8; ++kt) {
        v[2 * kt]     = *(const float4*)(rp + kt * 32);
        v[2 * kt + 1] = *(const float4*)(rp + kt * 32 + 4);
      }
      float s = 0.f, s2 = 0.f;
#pragma unroll
      for (int j = 0; j < 16; ++j) {
        s  += v[j].x + v[j].y + v[j].z + v[j].w;
        s2 += v[j].x * v[j].x + v[j].y * v[j].y + v[j].z * v[j].z + v[j].w * v[j].w;
      }
      s  += __shfl_xor(s, 16);  s  += __shfl_xor(s, 32);
      s2 += __shfl_xor(s2, 16); s2 += __shfl_xor(s2, 32);
      s += aux0 + aux1; s2 += aux0 + aux1;          // 0/1 flags: x == x^2
      const float mean = s * (1.0f / 258.0f);
      const float var  = s2 * (1.0f / 258.0f) - mean * mean;
      const float rstd = rsqrtf(var + 1e-5f);
      const float nm   = -mean * rstd;
      uint4* zf = rr ? zlnB : zlnA;
#pragma unroll
      for (int kt = 0; kt < 8; ++kt) {
        union { __bf16 h[8]; uint4 u; } cv;
#pragma unroll
        for (int q = 0; q < 4; ++q) {
          float x0 = (q < 2) ? ((q & 1) ? v[2*kt].z : v[2*kt].x)
                             : ((q & 1) ? v[2*kt+1].z : v[2*kt+1].x);
          float x1 = (q < 2) ? ((q & 1) ? v[2*kt].w : v[2*kt].y)
                             : ((q & 1) ? v[2*kt+1].w : v[2*kt+1].y);
          cv.h[2*q]   = (__bf16)__builtin_fmaf(x0, rstd, nm);
          cv.h[2*q+1] = (__bf16)__builtin_fmaf(x1, rstd, nm);
        }
        zf[kt] = cv.u;
      }
      if (rr) { za0b = __builtin_fmaf(aux0, rstd, nm); za1b = __builtin_fmaf(aux1, rstd, nm); }
      else    { za0a = __builtin_fmaf(aux0, rstd, nm); za1a = __builtin_fmaf(aux1, rstd, nm); }
    }

    // ---- GEMM1 (transposed): h1^T[n][m] in j-groups of 4; repack to h1 A-frags ----
    uint4 h1f[2][8];   // [mt][kt2]
#pragma unroll
    for (int jg = 0; jg < 4; ++jg) {
      f32x4 acc[4][2];   // [jl][mt]
#pragma unroll
      for (int jl = 0; jl < 4; ++jl) {
        const int j = jg * 4 + jl;
        f32x4 c0 = *(const f32x4*)&sC0[j * 16 + g * 4];
        f32x4 w6 = *(const f32x4*)&sW6[j * 16 + g * 4];
        f32x4 w7 = *(const f32x4*)&sW7[j * 16 + g * 4];
#pragma unroll
        for (int i = 0; i < 4; ++i) {
          acc[jl][0][i] = c0[i] + za0a * w6[i] + za1a * w7[i];
          acc[jl][1][i] = c0[i] + za0b * w6[i] + za1b * w7[i];
        }
      }
#pragma unroll
      for (int kt = 0; kt < 8; ++kt) {
        bf16x8 afr[4];
#pragma unroll
        for (int jl = 0; jl < 4; ++jl)
          afr[jl] = as_frag(*(const uint4*)(Wlds + (size_t)(kt * 16 + jg * 4 + jl) * 1024 + l * 16));
        bf16x8 bA = as_frag(zlnA[kt]), bB = as_frag(zlnB[kt]);
#pragma unroll
        for (int jl = 0; jl < 4; ++jl) {
          acc[jl][0] = __builtin_amdgcn_mfma_f32_16x16x32_bf16(afr[jl], bA, acc[jl][0], 0, 0, 0);
          acc[jl][1] = __builtin_amdgcn_mfma_f32_16x16x32_bf16(afr[jl], bB, acc[jl][1], 0, 0, 0);
        }
      }
      // gelu + pack pairs: pk[mt][jl][p] = bf16(gelu(acc[2p]), gelu(acc[2p+1]))
      unsigned pk[2][4][2];
#pragma unroll
      for (int mt = 0; mt < 2; ++mt)
#pragma unroll
        for (int jl = 0; jl < 4; ++jl) {
          pk[mt][jl][0] = pk2(gelu_f(acc[jl][mt][0]), gelu_f(acc[jl][mt][1]));
          pk[mt][jl][1] = pk2(gelu_f(acc[jl][mt][2]), gelu_f(acc[jl][mt][3]));
        }
      // shuffle h1^T -> h1 A-frags: kt2 = jg*2 + k2l; j-pair = {2*kt2, 2*kt2+1}
      // dst dword tt of frag(mt,kt2): pk[mt][2*k2l + (g>>1)][tt&1]
      //   from lane 16*(2*(g&1) + (tt>>1)) + lo
#pragma unroll
      for (int mt = 0; mt < 2; ++mt)
#pragma unroll
        for (int k2l = 0; k2l < 2; ++k2l) {
          unsigned dw[4];
#pragma unroll
          for (int tt = 0; tt < 4; ++tt) {
            int src = 16 * (2 * (g & 1) + (tt >> 1)) + lo;
            unsigned dE = __shfl(pk[mt][2 * k2l][tt & 1], src);
            unsigned dO = __shfl(pk[mt][2 * k2l + 1][tt & 1], src);
            dw[tt] = (g >= 2) ? dO : dE;
          }
          h1f[mt][jg * 2 + k2l] = make_uint4(dw[0], dw[1], dw[2], dw[3]);
        }
    }

    // ---- GEMM2: h2 = h1 @ W2 (B-frags from L2, triple-buffer depth-2), col-groups of 4 ----
    float plog[2][4];
#pragma unroll
    for (int mt = 0; mt < 2; ++mt)
#pragma unroll
      for (int i = 0; i < 4; ++i) plog[mt][i] = 0.f;

#pragma unroll
    for (int cq = 0; cq < 4; ++cq) {
      f32x4 acc2[4][2];  // [c4][mt]
#pragma unroll
      for (int c4 = 0; c4 < 4; ++c4) {
        float bb = sB2[(cq * 4 + c4) * 16 + lo];
#pragma unroll
        for (int mt = 0; mt < 2; ++mt)
#pragma unroll
          for (int i = 0; i < 4; ++i) acc2[c4][mt][i] = bb;
      }
      // frag addr: ((kt2*16 + cq*4 + c4)*1024) + l*16
      const char* wbase = W2c + (size_t)(cq * 4) * 1024 + (size_t)l * 16;
      uint4 bA[4], bB[4], bC[4];
#pragma unroll
      for (int c4 = 0; c4 < 4; ++c4) bA[c4] = *(const uint4*)(wbase + c4 * 1024);
#pragma unroll
      for (int c4 = 0; c4 < 4; ++c4) bB[c4] = *(const uint4*)(wbase + 16384 + c4 * 1024);
#pragma unroll
      for (int kt2 = 0; kt2 < 8; ++kt2) {
        // issue kt2+2 into the buffer freed at kt2-1 (depth-2 prefetch)
        if (kt2 < 6) {
          const char* pf = wbase + (size_t)(kt2 + 2) * 16384;
          if ((kt2 % 3) == 0) {
#pragma unroll
            for (int c4 = 0; c4 < 4; ++c4) bC[c4] = *(const uint4*)(pf + c4 * 1024);
          } else if ((kt2 % 3) == 1) {
#pragma unroll
            for (int c4 = 0; c4 < 4; ++c4) bA[c4] = *(const uint4*)(pf + c4 * 1024);
          } else {
#pragma unroll
            for (int c4 = 0; c4 < 4; ++c4) bB[c4] = *(const uint4*)(pf + c4 * 1024);
          }
        }
        bf16x8 a0 = as_frag(h1f[0][kt2]), a1 = as_frag(h1f[1][kt2]);
#pragma unroll
        for (int c4 = 0; c4 < 4; ++c4) {
          bf16x8 bf = as_frag((kt2 % 3) == 0 ? bA[c4] : (kt2 % 3) == 1 ? bB[c4] : bC[c4]);
          acc2[c4][0] = __builtin_amdgcn_mfma_f32_16x16x32_bf16(a0, bf, acc2[c4][0], 0, 0, 0);
          acc2[c4][1] = __builtin_amdgcn_mfma_f32_16x16x32_bf16(a1, bf, acc2[c4][1], 0, 0, 0);
        }
      }
      // gelu + logits partial + pooled for this col-group
#pragma unroll
      for (int c4 = 0; c4 < 4; ++c4) {
        float wv = sSelw[(cq * 4 + c4) * 16 + lo];
#pragma unroll
        for (int mt = 0; mt < 2; ++mt)
#pragma unroll
          for (int i = 0; i < 4; ++i) {
            acc2[c4][mt][i] = gelu_f(acc2[c4][mt][i]);
            plog[mt][i] += acc2[c4][mt][i] * wv;
          }
      }
      if (uniform) {
#pragma unroll
        for (int c4 = 0; c4 < 4; ++c4) {
          float pv = 0.f;
#pragma unroll
          for (int mt = 0; mt < 2; ++mt)
#pragma unroll
            for (int i = 0; i < 4; ++i) pv += acc2[c4][mt][i];
          pv += __shfl_xor(pv, 16);
          pv += __shfl_xor(pv, 32);
          if (l < 16) atomicAdd(&pooledAcc[g0s * 256 + (cq * 4 + c4) * 16 + l], pv);
        }
      } else {
        int gm[2][4];
#pragma unroll
        for (int mt = 0; mt < 2; ++mt)
#pragma unroll
          for (int i = 0; i < 4; ++i) gm[mt][i] = __shfl(gid, 16 * mt + 4 * g + i);
#pragma unroll
        for (int c4 = 0; c4 < 4; ++c4)
#pragma unroll
          for (int mt = 0; mt < 2; ++mt)
#pragma unroll
            for (int i = 0; i < 4; ++i)
              atomicAdd(&pooledAcc[gm[mt][i] * 256 + (cq * 4 + c4) * 16 + lo],
                        acc2[c4][mt][i]);
      }
    }

    // ---- logits: reduce over n2 lanes, add bonus, write ----
    float fm[2][4];
#pragma unroll
    for (int mt = 0; mt < 2; ++mt)
#pragma unroll
      for (int i = 0; i < 4; ++i) fm[mt][i] = __shfl(frontf, 16 * mt + 4 * g + i);
#pragma unroll
    for (int mt = 0; mt < 2; ++mt)
#pragma unroll
      for (int i = 0; i < 4; ++i) {
        float p = plog[mt][i];
        p += __shfl_xor(p, 1); p += __shfl_xor(p, 2);
        p += __shfl_xor(p, 4); p += __shfl_xor(p, 8);
        if (lo == 0)
          outLogits[base + 16 * mt + 4 * g + i] = p + selbr + 0.5f * fm[mt][i];
      }
  }
}

// ---------------------------------------------------------------------------
__global__ __launch_bounds__(256) void stop_kernel(
    const float* __restrict__ pooledAcc, const float* __restrict__ cnts,
    const float* __restrict__ qtok,
    const float* __restrict__ ln2g, const float* __restrict__ ln2b,
    const float* __restrict__ sW1, const float* __restrict__ sb1,
    const float* __restrict__ sW2, const float* __restrict__ sb2,
    float* __restrict__ outStop, float* __restrict__ outPooled) {
  __shared__ float sIn[512], sLn[512], sRed[8];
  const int t = threadIdx.x, g = blockIdx.x;
  const int w = t >> 6, l = t & 63;
  float c = fmaxf(cnts[g], 1.0f);
  float p = pooledAcc[g * 256 + t] / c;
  outPooled[g * 256 + t] = p;
  sIn[t] = p;
  sIn[256 + t] = qtok[g * 256 + t];
  __syncthreads();
  float a = sIn[t], b = sIn[256 + t];
  float s = a + b, s2 = a * a + b * b;
#pragma unroll
  for (int m = 1; m < 64; m <<= 1) { s += __shfl_xor(s, m); s2 += __shfl_xor(s2, m); }
  if (l == 0) { sRed[w] = s; sRed[4 + w] = s2; }
  __syncthreads();
  s  = sRed[0] + sRed[1] + sRed[2] + sRed[3];
  s2 = sRed[4] + sRed[5] + sRed[6] + sRed[7];
  const float mean = s * (1.0f / 512.0f);
  const float var  = s2 * (1.0f / 512.0f) - mean * mean;
  const float rstd = rsqrtf(var + 1e-5f);
  sLn[t]       = (a - mean) * rstd * ln2g[t] + ln2b[t];
  sLn[256 + t] = (b - mean) * rstd * ln2g[256 + t] + ln2b[256 + t];
  __syncthreads();
  float accv = sb1[t];
#pragma unroll 8
  for (int k = 0; k < 512; ++k) accv += sLn[k] * sW1[k * 256 + t];
  float u = gelu_f(accv);
  float part = u * sW2[t];
#pragma unroll
  for (int m = 1; m < 64; m <<= 1) part += __shfl_xor(part, m);
  if (l == 0) sRed[w] = part;
  __syncthreads();
  if (t == 0) outStop[g] = sRed[0] + sRed[1] + sRed[2] + sRed[3] + sb2[0];
}

// ---------------------------------------------------------------------------
extern "C" void kernel_launch(void* const* d_in, const int* in_sizes, int n_in,
                              void* d_out, int out_size, void* d_ws, size_t ws_size,
                              hipStream_t stream) {
  const float* tok   = (const float*)d_in[0];
  const float* qtok  = (const float*)d_in[1];
  const int* ebatch  = (const int*)d_in[2];
  const void* smask  = d_in[3];
  const int* eheads  = (const int*)d_in[4];
  const int* etails  = (const int*)d_in[5];
  const int* curtail = (const int*)d_in[6];
  const float* ln1g  = (const float*)d_in[7];
  const float* ln1b  = (const float*)d_in[8];
  const float* W1    = (const float*)d_in[9];
  const float* b1    = (const float*)d_in[10];
  const float* W2    = (const float*)d_in[11];
  const float* b2    = (const float*)d_in[12];
  const float* selw  = (const float*)d_in[13];
  const float* selb  = (const float*)d_in[14];
  const float* ln2g  = (const float*)d_in[15];
  const float* ln2b  = (const float*)d_in[16];
  const float* sW1   = (const float*)d_in[17];
  const float* sb1   = (const float*)d_in[18];
  const float* sW2   = (const float*)d_in[19];
  const float* sb2   = (const float*)d_in[20];

  const int E = in_sizes[2];            // 400000 (divisible by 32)
  const int G = in_sizes[1] / 256;      // 64

  char* ws = (char*)d_ws;
  __bf16* W1p   = (__bf16*)(ws);                 // 131072 B
  __bf16* W2p   = (__bf16*)(ws + 131072);        // 131072 B
  float*  C0    = (float*)(ws + 262144);
  float*  GW6   = (float*)(ws + 263168);
  float*  GW7   = (float*)(ws + 264192);
  float*  pooled= (float*)(ws + 265216);         // 65536 B
  float*  cnts  = (float*)(ws + 330752);         // 256 B
  int*    mflag = (int*)(ws + 331008);           // 4 B
  (void)ws_size; (void)n_in; (void)out_size;

  hipMemsetAsync(ws + 265216, 0, 65536 + 256, stream);  // pooled + counts

  prep_pack<<<64, 256, 0, stream>>>(W1, W2, ln1g, W1p, W2p);
  prep_vec<<<1, 1024, 0, stream>>>(W1, ln1g, ln1b, b1, (const unsigned*)smask,
                                   C0, GW6, GW7, mflag);
  edge_kernel<<<256, 512, 0, stream>>>(
      tok, ebatch, (const unsigned char*)smask, eheads, etails, curtail,
      W1p, W2p, C0, GW6, GW7, b2, selw, selb, mflag,
      (float*)d_out, pooled, cnts, E);
  stop_kernel<<<G, 256, 0, stream>>>(pooled, cnts, qtok, ln2g, ln2b,
                                     sW1, sb1, sW2, sb2,
                                     (float*)d_out + E, (float*)d_out + E + G);
}

// Round 7
// 552.658 us; speedup vs baseline: 2.7536x; 2.7536x over previous
//
#include <hip/hip_runtime.h>
#include <hip/hip_bf16.h>
#include <cstdint>

// EdgeFrontierPolicy: E=400000, G=64, H=256.
// Wave-independent, zero post-prologue barriers. W1^T frag-packed resident in
// LDS (128KB). Per 32-edge wave-tile:
//   mt-split: {2-pass LN -> zln(32 regs) -> G1 (h1^T = W1g^T x zln) -> gelu ->
//              pk-shuffle -> h1f[mt] (32 regs bf16 A/B-frags)}
//   G2 computed TRANSPOSED: h2^T = W2^T x h1^T. h1f's register layout is
//   simultaneously the A-frag of h1 and the B-frag of h1^T, so it feeds the
//   swapped-operand MFMA unchanged. W2 frags stream from L2 (2 MFMA/load).
// All phases sized to fit the 128-VGPR budget the allocator insists on
// (r4-r6: 190-reg design -> GBs of scratch spill at the pinned 128 cap).

typedef __bf16 bf16x8 __attribute__((ext_vector_type(8)));
typedef float  f32x4  __attribute__((ext_vector_type(4)));

typedef __attribute__((address_space(1))) const char gas_char;
typedef __attribute__((address_space(3))) char las_char;

__device__ __forceinline__ float gelu_f(float x) {
  float x2 = x * x;
  float t1 = __builtin_fmaf(0.1029444f, x2, 2.3022078f);
  float a  = x * t1;
  float e;
  asm("v_exp_f32 %0, %1" : "=v"(e) : "v"(a));
  float r;
  asm("v_rcp_f32 %0, %1" : "=v"(r) : "v"(e + 1.0f));
  return x - x * r;
}

__device__ __forceinline__ bf16x8 as_frag(uint4 u) {
  union { uint4 u; bf16x8 f; } c; c.u = u; return c.f;
}
__device__ __forceinline__ unsigned pk2(float a, float b) {
  union { __bf16 h[2]; unsigned u; } c;
  c.h[0] = (__bf16)a; c.h[1] = (__bf16)b; return c.u;
}

// ---------------------------------------------------------------------------
// Pack W1 (ln1_g folded) / W2 into MFMA frag order, bf16.
// out[((kt*16+nt)*64 + l)*8 + i] = W[32kt + 8*(l>>4)+i][16nt + (l&15)]
__global__ void prep_pack(const float* __restrict__ W1, const float* __restrict__ W2,
                          const float* __restrict__ ln1g,
                          __bf16* __restrict__ W1p, __bf16* __restrict__ W2p) {
  int gid = blockIdx.x * blockDim.x + threadIdx.x;   // 16384 threads
  int m  = gid >> 13;
  int b  = (gid >> 6) & 127;
  int l  = gid & 63;
  int kt = b >> 4, nt = b & 15;
  int k0 = kt * 32 + ((l >> 4) << 3);
  int n  = nt * 16 + (l & 15);
  const float* W = m ? W2 : W1;
  bf16x8 v;
#pragma unroll
  for (int i = 0; i < 8; ++i) {
    int k = k0 + i;
    float wv = W[k * 256 + n];
    if (!m) wv *= ln1g[k];
    v[i] = (__bf16)wv;
  }
  __bf16* dst = m ? W2p : W1p;
  *(bf16x8*)(dst + (size_t)(b * 64 + l) * 8) = v;
}

// C0/GW6/GW7 + mask dtype detect.
__global__ void prep_vec(const float* __restrict__ W1, const float* __restrict__ ln1g,
                         const float* __restrict__ ln1b, const float* __restrict__ b1,
                         const unsigned* __restrict__ smask_words,
                         float* __restrict__ C0, float* __restrict__ GW6,
                         float* __restrict__ GW7, int* __restrict__ maskIsByte) {
  __shared__ float red[4][256];
  const int n = threadIdx.x & 255, c = threadIdx.x >> 8;
  const int k0 = c * 64, k1 = (c == 3) ? 258 : k0 + 64;
  float s = 0.f;
#pragma unroll 4
  for (int k = k0; k < k1; ++k) s += ln1b[k] * W1[k * 256 + n];
  red[c][n] = s;
  __syncthreads();
  if (c == 0) {
    C0[n]  = b1[n] + red[0][n] + red[1][n] + red[2][n] + red[3][n];
    GW6[n] = ln1g[256] * W1[256 * 256 + n];
    GW7[n] = ln1g[257] * W1[257 * 256 + n];
  }
  if (threadIdx.x == 0) {
    int big = 0;
    for (int i = 0; i < 64; ++i) { if (smask_words[i] > 1u) big = 1; }
    *maskIsByte = big;
  }
}

// ---------------------------------------------------------------------------
__global__ __launch_bounds__(512) void edge_kernel(
    const float* __restrict__ tok, const int* __restrict__ ebatch,
    const unsigned char* __restrict__ smaskB,
    const int* __restrict__ eheads, const int* __restrict__ etails,
    const int* __restrict__ curtail,
    const __bf16* __restrict__ W1p, const __bf16* __restrict__ W2p,
    const float* __restrict__ C0v, const float* __restrict__ GW6v,
    const float* __restrict__ GW7v, const float* __restrict__ b2v,
    const float* __restrict__ selwv, const float* __restrict__ selbv,
    const int* __restrict__ maskFlag,
    float* __restrict__ outLogits, float* __restrict__ pooledAcc,
    float* __restrict__ cnts, int E) {
  __shared__ __align__(16) char Wlds[131072];     // W1^T frag-packed, resident

  const int t  = threadIdx.x;
  const int w  = t >> 6, l = t & 63;
  const int lo = l & 15, g = l >> 4;

  // ---- prologue: stage W1^T -> LDS (wave-linear 16KB each) ----
  {
    const char* Wsrc = (const char*)W1p;
    unsigned woff = __builtin_amdgcn_readfirstlane((unsigned)w * 16384u);
#pragma unroll
    for (int it = 0; it < 16; ++it)
      __builtin_amdgcn_global_load_lds((gas_char*)(Wsrc + woff + it * 1024 + l * 16),
                                       (las_char*)(Wlds + woff + it * 1024), 16, 0, 0);
  }
  const int   mb    = *maskFlag;
  const float selbr = selbv[0];
  __syncthreads();   // drains global_load_lds; LAST barrier in the kernel

  const int totalTiles = E >> 5;                 // 32 edges per tile
  const int nWaves = gridDim.x * 8;
  const char* W2c = (const char*)W2p;

  for (int tile = blockIdx.x * 8 + w; tile < totalTiles; tile += nWaves) {
    const int base = tile << 5;

    // ---- flags (lanes 0..31, one edge each) ----
    float candf = 0.f, frontf = 0.f; int gid = 0;
    if (l < 32) {
      int ge = base + l;
      gid = ebatch[ge];
      int mv = mb ? (int)smaskB[ge] : ((const int*)smaskB)[ge];
      int cand = (mv == 0);
      int cur  = curtail[gid];
      int fr   = cand && ((eheads[ge] == cur) || (etails[ge] == cur));
      candf = (float)cand; frontf = (float)fr;
    }
    const int g0s = __shfl(gid, 0);
    const bool uniform = (__ballot((l < 32) ? (gid == g0s) : 1) == ~0ull);
    {  // counts: boundary lanes add run lengths
      int gp = __shfl(gid, (l == 0) ? 0 : l - 1);
      bool isb = (l < 32) && (l == 0 || gid != gp);
      unsigned long long bm = __ballot(isb);
      if (isb) {
        unsigned long long m2 = bm >> (l + 1);
        int run = m2 ? (int)__ffsll((long long)m2) : (32 - l);
        atomicAdd(&cnts[gid], (float)run);
      }
    }
    // flags to row owners (edge a = lo, edge b = 16+lo)
    const float ca  = __shfl(candf, lo),      fa  = __shfl(frontf, lo);
    const float cb_ = __shfl(candf, 16 + lo), fb_ = __shfl(frontf, 16 + lo);
    const int   ga  = __shfl(gid, lo),        gb  = __shfl(gid, 16 + lo);

    uint4 h1f[2][8];   // h1 frags: A-frag of h1 == B-frag of h1^T

    // ==== per edge-half: 2-pass LN -> zln -> G1 -> gelu -> shuffle -> h1f ====
#pragma unroll
    for (int mt = 0; mt < 2; ++mt) {
      const float aux0 = mt ? cb_ : ca, aux1 = mt ? fb_ : fa;
      const float* rp = tok + (size_t)(base + mt * 16 + lo) * 256 + (g << 3);

      // pass 1: stats only (values discarded -> low pressure)
      float s = 0.f, s2 = 0.f;
#pragma unroll
      for (int kt = 0; kt < 8; ++kt) {
        float4 x0 = *(const float4*)(rp + kt * 32);
        float4 x1 = *(const float4*)(rp + kt * 32 + 4);
        s  += x0.x + x0.y + x0.z + x0.w + x1.x + x1.y + x1.z + x1.w;
        s2 += x0.x*x0.x + x0.y*x0.y + x0.z*x0.z + x0.w*x0.w
            + x1.x*x1.x + x1.y*x1.y + x1.z*x1.z + x1.w*x1.w;
      }
      s  += __shfl_xor(s, 16);  s  += __shfl_xor(s, 32);
      s2 += __shfl_xor(s2, 16); s2 += __shfl_xor(s2, 32);
      s += aux0 + aux1; s2 += aux0 + aux1;          // 0/1 flags: x == x^2
      const float mean = s * (1.0f / 258.0f);
      const float var  = s2 * (1.0f / 258.0f) - mean * mean;
      const float rstd = rsqrtf(var + 1e-5f);
      const float nm   = -mean * rstd;
      const float za0  = __builtin_fmaf(aux0, rstd, nm);
      const float za1  = __builtin_fmaf(aux1, rstd, nm);

      // pass 2: reload (L2-hot; opaque ptr defeats CSE with pass 1) + pack
      const float* rp2 = rp;
      asm volatile("" : "+v"(rp2));
      uint4 zln[8];
#pragma unroll
      for (int kt = 0; kt < 8; ++kt) {
        float4 x0 = *(const float4*)(rp2 + kt * 32);
        float4 x1 = *(const float4*)(rp2 + kt * 32 + 4);
        union { __bf16 h[8]; uint4 u; } cv;
        cv.h[0] = (__bf16)__builtin_fmaf(x0.x, rstd, nm);
        cv.h[1] = (__bf16)__builtin_fmaf(x0.y, rstd, nm);
        cv.h[2] = (__bf16)__builtin_fmaf(x0.z, rstd, nm);
        cv.h[3] = (__bf16)__builtin_fmaf(x0.w, rstd, nm);
        cv.h[4] = (__bf16)__builtin_fmaf(x1.x, rstd, nm);
        cv.h[5] = (__bf16)__builtin_fmaf(x1.y, rstd, nm);
        cv.h[6] = (__bf16)__builtin_fmaf(x1.z, rstd, nm);
        cv.h[7] = (__bf16)__builtin_fmaf(x1.w, rstd, nm);
        zln[kt] = cv.u;
      }

      // G1: h1^T[j][edge16] = W1g^T x zln, j-groups of 4
#pragma unroll
      for (int jg = 0; jg < 4; ++jg) {
        f32x4 acc[4];
#pragma unroll
        for (int jl = 0; jl < 4; ++jl) {
          const int j16 = (jg * 4 + jl) * 16 + g * 4;
          f32x4 c0 = *(const f32x4*)(C0v + j16);
          f32x4 w6 = *(const f32x4*)(GW6v + j16);
          f32x4 w7 = *(const f32x4*)(GW7v + j16);
#pragma unroll
          for (int i = 0; i < 4; ++i)
            acc[jl][i] = c0[i] + za0 * w6[i] + za1 * w7[i];
        }
#pragma unroll
        for (int kt = 0; kt < 8; ++kt) {
          bf16x8 bz = as_frag(zln[kt]);
#pragma unroll
          for (int jl = 0; jl < 4; ++jl) {
            bf16x8 afr = as_frag(*(const uint4*)(
                Wlds + (size_t)((kt * 16 + jg * 4 + jl) * 1024) + l * 16));
            acc[jl] = __builtin_amdgcn_mfma_f32_16x16x32_bf16(afr, bz, acc[jl], 0, 0, 0);
          }
        }
        // gelu + pack
        unsigned pk[4][2];
#pragma unroll
        for (int jl = 0; jl < 4; ++jl) {
          pk[jl][0] = pk2(gelu_f(acc[jl][0]), gelu_f(acc[jl][1]));
          pk[jl][1] = pk2(gelu_f(acc[jl][2]), gelu_f(acc[jl][3]));
        }
        // shuffle h1^T -> h1 frags (verified r4-r6)
#pragma unroll
        for (int k2l = 0; k2l < 2; ++k2l) {
          unsigned dw[4];
#pragma unroll
          for (int tt = 0; tt < 4; ++tt) {
            int src = 16 * (2 * (g & 1) + (tt >> 1)) + lo;
            unsigned dE = __shfl(pk[2 * k2l][tt & 1], src);
            unsigned dO = __shfl(pk[2 * k2l + 1][tt & 1], src);
            dw[tt] = (g >= 2) ? dO : dE;
          }
          h1f[mt][jg * 2 + k2l] = make_uint4(dw[0], dw[1], dw[2], dw[3]);
        }
      }
    }  // mt

    asm volatile("" ::: "memory");   // fence: keep G2 loads out of G1's window

    // ==== G2^T: h2^T = W2^T x h1^T; A=W2p frag (L2), B=h1f (regs) ====
    float plog0 = 0.f, plog1 = 0.f;
#pragma unroll 4
    for (int cb = 0; cb < 16; ++cb) {
      f32x4 bb = *(const f32x4*)(b2v   + cb * 16 + g * 4);
      f32x4 sw = *(const f32x4*)(selwv + cb * 16 + g * 4);
      f32x4 a0 = bb, a1 = bb;
      const char* wb = W2c + (size_t)(cb * 1024) + l * 16;
      uint4 wf[4];
#pragma unroll
      for (int p = 0; p < 4; ++p) wf[p] = *(const uint4*)(wb + p * 16384);
#pragma unroll
      for (int kt2 = 0; kt2 < 8; ++kt2) {
        bf16x8 af = as_frag(wf[kt2 & 3]);
        if (kt2 < 4) wf[kt2 & 3] = *(const uint4*)(wb + (size_t)(kt2 + 4) * 16384);
        a0 = __builtin_amdgcn_mfma_f32_16x16x32_bf16(af, as_frag(h1f[0][kt2]), a0, 0, 0, 0);
        a1 = __builtin_amdgcn_mfma_f32_16x16x32_bf16(af, as_frag(h1f[1][kt2]), a1, 0, 0, 0);
      }
      // D: col=lo=edge, row=4g+i -> global col = 16cb+4g+i
      f32x4 v0, v1;
#pragma unroll
      for (int i = 0; i < 4; ++i) { v0[i] = gelu_f(a0[i]); v1[i] = gelu_f(a1[i]); }
      plog0 += v0[0]*sw[0] + v0[1]*sw[1] + v0[2]*sw[2] + v0[3]*sw[3];
      plog1 += v1[0]*sw[0] + v1[1]*sw[1] + v1[2]*sw[2] + v1[3]*sw[3];
      if (uniform) {
        f32x4 sv;
#pragma unroll
        for (int i = 0; i < 4; ++i) sv[i] = v0[i] + v1[i];
#pragma unroll
        for (int st = 1; st < 16; st <<= 1) {
#pragma unroll
          for (int i = 0; i < 4; ++i) sv[i] += __shfl_xor(sv[i], st);
        }
        if (lo == 0) {
#pragma unroll
          for (int i = 0; i < 4; ++i)
            atomicAdd(&pooledAcc[g0s * 256 + cb * 16 + g * 4 + i], sv[i]);
        }
      } else {
#pragma unroll
        for (int i = 0; i < 4; ++i) {
          atomicAdd(&pooledAcc[ga * 256 + cb * 16 + g * 4 + i], v0[i]);
          atomicAdd(&pooledAcc[gb * 256 + cb * 16 + g * 4 + i], v1[i]);
        }
      }
    }

    // ---- logits: reduce partials across g-groups, add bias + bonus ----
    plog0 += __shfl_xor(plog0, 16); plog0 += __shfl_xor(plog0, 32);
    plog1 += __shfl_xor(plog1, 16); plog1 += __shfl_xor(plog1, 32);
    if (l < 16) {
      outLogits[base + l]      = plog0 + selbr + 0.5f * fa;
      outLogits[base + 16 + l] = plog1 + selbr + 0.5f * fb_;
    }
  }
}

// ---------------------------------------------------------------------------
__global__ __launch_bounds__(256) void stop_kernel(
    const float* __restrict__ pooledAcc, const float* __restrict__ cnts,
    const float* __restrict__ qtok,
    const float* __restrict__ ln2g, const float* __restrict__ ln2b,
    const float* __restrict__ sW1, const float* __restrict__ sb1,
    const float* __restrict__ sW2, const float* __restrict__ sb2,
    float* __restrict__ outStop, float* __restrict__ outPooled) {
  __shared__ float sIn[512], sLn[512], sRed[8];
  const int t = threadIdx.x, g = blockIdx.x;
  const int w = t >> 6, l = t & 63;
  float c = fmaxf(cnts[g], 1.0f);
  float p = pooledAcc[g * 256 + t] / c;
  outPooled[g * 256 + t] = p;
  sIn[t] = p;
  sIn[256 + t] = qtok[g * 256 + t];
  __syncthreads();
  float a = sIn[t], b = sIn[256 + t];
  float s = a + b, s2 = a * a + b * b;
#pragma unroll
  for (int m = 1; m < 64; m <<= 1) { s += __shfl_xor(s, m); s2 += __shfl_xor(s2, m); }
  if (l == 0) { sRed[w] = s; sRed[4 + w] = s2; }
  __syncthreads();
  s  = sRed[0] + sRed[1] + sRed[2] + sRed[3];
  s2 = sRed[4] + sRed[5] + sRed[6] + sRed[7];
  const float mean = s * (1.0f / 512.0f);
  const float var  = s2 * (1.0f / 512.0f) - mean * mean;
  const float rstd = rsqrtf(var + 1e-5f);
  sLn[t]       = (a - mean) * rstd * ln2g[t] + ln2b[t];
  sLn[256 + t] = (b - mean) * rstd * ln2g[256 + t] + ln2b[256 + t];
  __syncthreads();
  float accv = sb1[t];
#pragma unroll 8
  for (int k = 0; k < 512; ++k) accv += sLn[k] * sW1[k * 256 + t];
  float u = gelu_f(accv);
  float part = u * sW2[t];
#pragma unroll
  for (int m = 1; m < 64; m <<= 1) part += __shfl_xor(part, m);
  if (l == 0) sRed[w] = part;
  __syncthreads();
  if (t == 0) outStop[g] = sRed[0] + sRed[1] + sRed[2] + sRed[3] + sb2[0];
}

// ---------------------------------------------------------------------------
extern "C" void kernel_launch(void* const* d_in, const int* in_sizes, int n_in,
                              void* d_out, int out_size, void* d_ws, size_t ws_size,
                              hipStream_t stream) {
  const float* tok   = (const float*)d_in[0];
  const float* qtok  = (const float*)d_in[1];
  const int* ebatch  = (const int*)d_in[2];
  const void* smask  = d_in[3];
  const int* eheads  = (const int*)d_in[4];
  const int* etails  = (const int*)d_in[5];
  const int* curtail = (const int*)d_in[6];
  const float* ln1g  = (const float*)d_in[7];
  const float* ln1b  = (const float*)d_in[8];
  const float* W1    = (const float*)d_in[9];
  const float* b1    = (const float*)d_in[10];
  const float* W2    = (const float*)d_in[11];
  const float* b2    = (const float*)d_in[12];
  const float* selw  = (const float*)d_in[13];
  const float* selb  = (const float*)d_in[14];
  const float* ln2g  = (const float*)d_in[15];
  const float* ln2b  = (const float*)d_in[16];
  const float* sW1   = (const float*)d_in[17];
  const float* sb1   = (const float*)d_in[18];
  const float* sW2   = (const float*)d_in[19];
  const float* sb2   = (const float*)d_in[20];

  const int E = in_sizes[2];            // 400000 (divisible by 32)
  const int G = in_sizes[1] / 256;      // 64

  char* ws = (char*)d_ws;
  __bf16* W1p   = (__bf16*)(ws);                 // 131072 B
  __bf16* W2p   = (__bf16*)(ws + 131072);        // 131072 B
  float*  C0    = (float*)(ws + 262144);
  float*  GW6   = (float*)(ws + 263168);
  float*  GW7   = (float*)(ws + 264192);
  float*  pooled= (float*)(ws + 265216);         // 65536 B
  float*  cnts  = (float*)(ws + 330752);         // 256 B
  int*    mflag = (int*)(ws + 331008);           // 4 B
  (void)ws_size; (void)n_in; (void)out_size;

  hipMemsetAsync(ws + 265216, 0, 65536 + 256, stream);  // pooled + counts

  prep_pack<<<64, 256, 0, stream>>>(W1, W2, ln1g, W1p, W2p);
  prep_vec<<<1, 1024, 0, stream>>>(W1, ln1g, ln1b, b1, (const unsigned*)smask,
                                   C0, GW6, GW7, mflag);
  edge_kernel<<<256, 512, 0, stream>>>(
      tok, ebatch, (const unsigned char*)smask, eheads, etails, curtail,
      W1p, W2p, C0, GW6, GW7, b2, selw, selb, mflag,
      (float*)d_out, pooled, cnts, E);
  stop_kernel<<<G, 256, 0, stream>>>(pooled, cnts, qtok, ln2g, ln2b,
                                     sW1, sb1, sW2, sb2,
                                     (float*)d_out + E, (float*)d_out + E + G);
}

// Round 8
// 318.621 us; speedup vs baseline: 4.7762x; 1.7345x over previous
//
#include <hip/hip_runtime.h>
#include <hip/hip_bf16.h>
#include <cstdint>

// EdgeFrontierPolicy: E=400000, G=64, H=256.
// r3 cooperative structure (verified, 342us) with B-staging removed:
// weights are L2-resident (256KB packed) -> each wave reads its B-frags
// directly from global with a register double-buffer. Barriers: 18 -> 4 per
// block. LDS 67.6 -> 34.8KB => 4 blocks/CU = 16 waves/CU for latency hiding.

typedef __bf16 bf16x8 __attribute__((ext_vector_type(8)));
typedef float  f32x4  __attribute__((ext_vector_type(4)));

__device__ __forceinline__ float gelu_f(float x) {
  float x2 = x * x;
  float t1 = __builtin_fmaf(0.1029444f, x2, 2.3022078f);
  float a  = x * t1;
  float e;
  asm("v_exp_f32 %0, %1" : "=v"(e) : "v"(a));
  float r;
  asm("v_rcp_f32 %0, %1" : "=v"(r) : "v"(e + 1.0f));
  return x - x * r;
}

__device__ __forceinline__ bf16x8 as_frag(uint4 u) {
  union { uint4 u; bf16x8 f; } c; c.u = u; return c.f;
}

// ---------------------------------------------------------------------------
// Pack W1 (ln1_g folded) / W2 into MFMA-B fragment order, bf16.
// frag(kt,nt) lane l: byte (kt*16+nt)*1024 + l*16.
__global__ void prep_pack(const float* __restrict__ W1, const float* __restrict__ W2,
                          const float* __restrict__ ln1g,
                          __bf16* __restrict__ W1p, __bf16* __restrict__ W2p) {
  int gid = blockIdx.x * blockDim.x + threadIdx.x;   // 16384 threads
  int m  = gid >> 13;
  int b  = (gid >> 6) & 127;
  int l  = gid & 63;
  int kt = b >> 4, nt = b & 15;
  int k0 = kt * 32 + ((l >> 4) << 3);
  int n  = nt * 16 + (l & 15);
  const float* W = m ? W2 : W1;
  bf16x8 v;
#pragma unroll
  for (int i = 0; i < 8; ++i) {
    int k = k0 + i;
    float wv = W[k * 256 + n];
    if (!m) wv *= ln1g[k];
    v[i] = (__bf16)wv;
  }
  __bf16* dst = m ? W2p : W1p;
  *(bf16x8*)(dst + (size_t)(b * 64 + l) * 8) = v;
}

// C0/GW6/GW7 + mask dtype detect.
__global__ void prep_vec(const float* __restrict__ W1, const float* __restrict__ ln1g,
                         const float* __restrict__ ln1b, const float* __restrict__ b1,
                         const unsigned* __restrict__ smask_words,
                         float* __restrict__ C0, float* __restrict__ GW6,
                         float* __restrict__ GW7, int* __restrict__ maskIsByte) {
  __shared__ float red[4][256];
  const int n = threadIdx.x & 255, c = threadIdx.x >> 8;
  const int k0 = c * 64, k1 = (c == 3) ? 258 : k0 + 64;
  float s = 0.f;
#pragma unroll 4
  for (int k = k0; k < k1; ++k) s += ln1b[k] * W1[k * 256 + n];
  red[c][n] = s;
  __syncthreads();
  if (c == 0) {
    C0[n]  = b1[n] + red[0][n] + red[1][n] + red[2][n] + red[3][n];
    GW6[n] = ln1g[256] * W1[256 * 256 + n];
    GW7[n] = ln1g[257] * W1[257 * 256 + n];
  }
  if (threadIdx.x == 0) {
    int big = 0;
    for (int i = 0; i < 64; ++i) { if (smask_words[i] > 1u) big = 1; }
    *maskIsByte = big;
  }
}

// ---------------------------------------------------------------------------
#define EPB 64

// 8 K-steps; B-frags from global (L2-hot, reg double-buffer); NO barriers.
__device__ __forceinline__ void gemm8_reg(const char* __restrict__ Wp,
                                          const char* aBase, unsigned swA,
                                          unsigned gA, int bOff,
                                          f32x4 (&acc)[4][4]) {
  uint4 bv[4], bn[4];
#pragma unroll
  for (int cf = 0; cf < 4; ++cf)
    bv[cf] = *(const uint4*)(Wp + bOff + (cf << 10));
#pragma unroll
  for (int kt = 0; kt < 8; ++kt) {
    if (kt < 7) {
#pragma unroll
      for (int cf = 0; cf < 4; ++cf)
        bn[cf] = *(const uint4*)(Wp + (kt + 1) * 16384 + bOff + (cf << 10));
    }
    bf16x8 av[4];
#pragma unroll
    for (int rf = 0; rf < 4; ++rf)
      av[rf] = *(const bf16x8*)(aBase + rf * 8192 + (((unsigned)(kt * 64) + gA) ^ swA));
#pragma unroll
    for (int rf = 0; rf < 4; ++rf)
#pragma unroll
      for (int cf = 0; cf < 4; ++cf)
        acc[rf][cf] = __builtin_amdgcn_mfma_f32_16x16x32_bf16(av[rf], as_frag(bv[cf]),
                                                              acc[rf][cf], 0, 0, 0);
#pragma unroll
    for (int cf = 0; cf < 4; ++cf) bv[cf] = bn[cf];
  }
}

__global__ __launch_bounds__(256) void edge_kernel(
    const float* __restrict__ tok, const int* __restrict__ ebatch,
    const unsigned char* __restrict__ smaskB,
    const int* __restrict__ eheads, const int* __restrict__ etails,
    const int* __restrict__ curtail,
    const __bf16* __restrict__ W1p, const __bf16* __restrict__ W2p,
    const float* __restrict__ C0v, const float* __restrict__ GW6v,
    const float* __restrict__ GW7v, const float* __restrict__ b2v,
    const float* __restrict__ selwv, const float* __restrict__ selbv,
    const int* __restrict__ maskFlag,
    float* __restrict__ outLogits, float* __restrict__ pooledAcc,
    float* __restrict__ cnts) {
  __shared__ __align__(16) char As_[64 * 512];          // 32KB, XOR-swizzled rows
  __shared__ float sZa0[64], sZa1[64], sFront[64];
  __shared__ float sLog[64][4];
  __shared__ int sG[64];

  const int t = threadIdx.x;
  const int w = t >> 6, l = t & 63;
  const int base = blockIdx.x * EPB;

  // ---- flags ----
  if (t < 64) {
    int ge = base + t;
    int g  = ebatch[ge];
    int mb = *maskFlag;
    int mv = mb ? (int)smaskB[ge] : ((const int*)smaskB)[ge];
    int cand = (mv == 0);
    int cur  = curtail[g];
    int fr   = cand && ((eheads[ge] == cur) || (etails[ge] == cur));
    sZa0[t] = (float)cand; sZa1[t] = (float)fr; sFront[t] = (float)fr; sG[t] = g;
  }
  __syncthreads();

  if (t == 0) {  // counts: run-length over sorted graph ids (overlaps LN)
    int cg = sG[0]; float run = 1.f;
    for (int e = 1; e < EPB; ++e) {
      int g = sG[e];
      if (g == cg) run += 1.f;
      else { atomicAdd(&cnts[cg], run); cg = g; run = 1.f; }
    }
    atomicAdd(&cnts[cg], run);
  }

  // ---- LayerNorm over 258 (4 threads/edge), bf16 A tile, XOR-swizzled ----
  {
    const int e = t >> 2, q = t & 3;
    const float* rp = tok + (size_t)(base + e) * 256 + q * 4;
    float4 v[16];
    float s = 0.f, s2 = 0.f;
#pragma unroll
    for (int j = 0; j < 16; ++j) {
      v[j] = *(const float4*)(rp + j * 16);
      s  += v[j].x + v[j].y + v[j].z + v[j].w;
      s2 += v[j].x * v[j].x + v[j].y * v[j].y + v[j].z * v[j].z + v[j].w * v[j].w;
    }
    float a0 = 0.f, a1 = 0.f;
    if (q == 0) { a0 = sZa0[e]; a1 = sZa1[e]; s += a0 + a1; s2 += a0 + a1; }
    s  += __shfl_xor(s, 1);  s  += __shfl_xor(s, 2);
    s2 += __shfl_xor(s2, 1); s2 += __shfl_xor(s2, 2);
    const float mean = s * (1.0f / 258.0f);
    const float var  = s2 * (1.0f / 258.0f) - mean * mean;
    const float rstd = rsqrtf(var + 1e-5f);
    const unsigned sw = (unsigned)(e & 7) << 4;
#pragma unroll
    for (int j = 0; j < 16; ++j) {
      union { __bf16 h[4]; uint2 u; } cv;
      cv.h[0] = (__bf16)((v[j].x - mean) * rstd);
      cv.h[1] = (__bf16)((v[j].y - mean) * rstd);
      cv.h[2] = (__bf16)((v[j].z - mean) * rstd);
      cv.h[3] = (__bf16)((v[j].w - mean) * rstd);
      unsigned off = (unsigned)(q * 8 + j * 32);
      *(uint2*)(As_ + e * 512 + (off ^ sw)) = cv.u;
    }
    if (q == 0) {
      sZa0[e] = (a0 - mean) * rstd;
      sZa1[e] = (a1 - mean) * rstd;
    }
  }
  __syncthreads();   // barrier 1: A tile + normalized aux visible

  // ---- per-thread geometry + acc init (C0 + rank-2 aux) ----
  const int rA = l & 15;
  const int r0 = (l >> 4) << 2;
  f32x4 acc[4][4];
  {
    float c0r[4], w6r[4], w7r[4];
#pragma unroll
    for (int cf = 0; cf < 4; ++cf) {
      int col = w * 64 + cf * 16 + rA;
      c0r[cf] = C0v[col]; w6r[cf] = GW6v[col]; w7r[cf] = GW7v[col];
    }
    f32x4 za0q[4], za1q[4];
#pragma unroll
    for (int rf = 0; rf < 4; ++rf) {
      za0q[rf] = *(const f32x4*)&sZa0[rf * 16 + r0];
      za1q[rf] = *(const f32x4*)&sZa1[rf * 16 + r0];
    }
#pragma unroll
    for (int rf = 0; rf < 4; ++rf)
#pragma unroll
      for (int cf = 0; cf < 4; ++cf)
#pragma unroll
        for (int i = 0; i < 4; ++i)
          acc[rf][cf][i] = c0r[cf] + za0q[rf][i] * w6r[cf] + za1q[rf][i] * w7r[cf];
  }

  const unsigned swA = (unsigned)(rA & 7) << 4;
  const unsigned gA  = (unsigned)((l >> 4) << 4);
  const char* aBase  = As_ + rA * 512;
  const int bOff     = (w << 12) + (l << 4);

  // ---- GEMM1 (B from L2, no barriers) ----
  gemm8_reg((const char*)W1p, aBase, swA, gA, bOff, acc);
  __syncthreads();   // barrier 2: all GEMM1 A-reads complete

  // ---- epilogue 1: gelu -> bf16 back into A tile ----
#pragma unroll
  for (int rf = 0; rf < 4; ++rf)
#pragma unroll
    for (int i = 0; i < 4; ++i) {
      int row = rf * 16 + r0 + i;
      char* rowp = As_ + row * 512;
      unsigned sw = (unsigned)(row & 7) << 4;
#pragma unroll
      for (int cf = 0; cf < 4; ++cf) {
        int col = w * 64 + cf * 16 + rA;
        *(__bf16*)(rowp + (((unsigned)(col * 2)) ^ sw)) = (__bf16)gelu_f(acc[rf][cf][i]);
      }
    }
  __syncthreads();   // barrier 3: h1 visible

  // ---- GEMM2 ----
#pragma unroll
  for (int cf = 0; cf < 4; ++cf) {
    float bb = b2v[w * 64 + cf * 16 + rA];
#pragma unroll
    for (int rf = 0; rf < 4; ++rf)
#pragma unroll
      for (int i = 0; i < 4; ++i) acc[rf][cf][i] = bb;
  }
  gemm8_reg((const char*)W2p, aBase, swA, gA, bOff, acc);

  // ---- epilogue 2: gelu -> logits + pooled ----
#pragma unroll
  for (int rf = 0; rf < 4; ++rf)
#pragma unroll
    for (int cf = 0; cf < 4; ++cf)
#pragma unroll
      for (int i = 0; i < 4; ++i) acc[rf][cf][i] = gelu_f(acc[rf][cf][i]);

  {
    float lwr[4];
#pragma unroll
    for (int cf = 0; cf < 4; ++cf) lwr[cf] = selwv[w * 64 + cf * 16 + rA];
#pragma unroll
    for (int rf = 0; rf < 4; ++rf)
#pragma unroll
      for (int i = 0; i < 4; ++i) {
        float p = acc[rf][0][i] * lwr[0] + acc[rf][1][i] * lwr[1]
                + acc[rf][2][i] * lwr[2] + acc[rf][3][i] * lwr[3];
        p += __shfl_xor(p, 1); p += __shfl_xor(p, 2);
        p += __shfl_xor(p, 4); p += __shfl_xor(p, 8);
        if (rA == 0) sLog[rf * 16 + r0 + i][w] = p;
      }
  }
  __syncthreads();   // barrier 4: sLog complete
  if (t < 64)
    outLogits[base + t] = sLog[t][0] + sLog[t][1] + sLog[t][2] + sLog[t][3]
                        + selbv[0] + 0.5f * sFront[t];

  if (sG[0] == sG[EPB - 1]) {
    int g = sG[0];
#pragma unroll
    for (int cf = 0; cf < 4; ++cf) {
      float sv = 0.f;
#pragma unroll
      for (int rf = 0; rf < 4; ++rf)
#pragma unroll
        for (int i = 0; i < 4; ++i) sv += acc[rf][cf][i];
      sv += __shfl_xor(sv, 16);
      sv += __shfl_xor(sv, 32);
      if (l < 16) atomicAdd(&pooledAcc[g * 256 + w * 64 + cf * 16 + l], sv);
    }
  } else {  // graph-boundary block (rare)
#pragma unroll
    for (int rf = 0; rf < 4; ++rf)
#pragma unroll
      for (int i = 0; i < 4; ++i) {
        int row = rf * 16 + r0 + i;
        int g = sG[row];
#pragma unroll
        for (int cf = 0; cf < 4; ++cf)
          atomicAdd(&pooledAcc[g * 256 + w * 64 + cf * 16 + rA], acc[rf][cf][i]);
      }
  }
}

// ---------------------------------------------------------------------------
__global__ __launch_bounds__(256) void stop_kernel(
    const float* __restrict__ pooledAcc, const float* __restrict__ cnts,
    const float* __restrict__ qtok,
    const float* __restrict__ ln2g, const float* __restrict__ ln2b,
    const float* __restrict__ sW1, const float* __restrict__ sb1,
    const float* __restrict__ sW2, const float* __restrict__ sb2,
    float* __restrict__ outStop, float* __restrict__ outPooled) {
  __shared__ float sIn[512], sLn[512], sRed[8];
  const int t = threadIdx.x, g = blockIdx.x;
  const int w = t >> 6, l = t & 63;
  float c = fmaxf(cnts[g], 1.0f);
  float p = pooledAcc[g * 256 + t] / c;
  outPooled[g * 256 + t] = p;
  sIn[t] = p;
  sIn[256 + t] = qtok[g * 256 + t];
  __syncthreads();
  float a = sIn[t], b = sIn[256 + t];
  float s = a + b, s2 = a * a + b * b;
#pragma unroll
  for (int m = 1; m < 64; m <<= 1) { s += __shfl_xor(s, m); s2 += __shfl_xor(s2, m); }
  if (l == 0) { sRed[w] = s; sRed[4 + w] = s2; }
  __syncthreads();
  s  = sRed[0] + sRed[1] + sRed[2] + sRed[3];
  s2 = sRed[4] + sRed[5] + sRed[6] + sRed[7];
  const float mean = s * (1.0f / 512.0f);
  const float var  = s2 * (1.0f / 512.0f) - mean * mean;
  const float rstd = rsqrtf(var + 1e-5f);
  sLn[t]       = (a - mean) * rstd * ln2g[t] + ln2b[t];
  sLn[256 + t] = (b - mean) * rstd * ln2g[256 + t] + ln2b[256 + t];
  __syncthreads();
  float accv = sb1[t];
#pragma unroll 8
  for (int k = 0; k < 512; ++k) accv += sLn[k] * sW1[k * 256 + t];
  float u = gelu_f(accv);
  float part = u * sW2[t];
#pragma unroll
  for (int m = 1; m < 64; m <<= 1) part += __shfl_xor(part, m);
  if (l == 0) sRed[w] = part;
  __syncthreads();
  if (t == 0) outStop[g] = sRed[0] + sRed[1] + sRed[2] + sRed[3] + sb2[0];
}

// ---------------------------------------------------------------------------
extern "C" void kernel_launch(void* const* d_in, const int* in_sizes, int n_in,
                              void* d_out, int out_size, void* d_ws, size_t ws_size,
                              hipStream_t stream) {
  const float* tok   = (const float*)d_in[0];
  const float* qtok  = (const float*)d_in[1];
  const int* ebatch  = (const int*)d_in[2];
  const void* smask  = d_in[3];
  const int* eheads  = (const int*)d_in[4];
  const int* etails  = (const int*)d_in[5];
  const int* curtail = (const int*)d_in[6];
  const float* ln1g  = (const float*)d_in[7];
  const float* ln1b  = (const float*)d_in[8];
  const float* W1    = (const float*)d_in[9];
  const float* b1    = (const float*)d_in[10];
  const float* W2    = (const float*)d_in[11];
  const float* b2    = (const float*)d_in[12];
  const float* selw  = (const float*)d_in[13];
  const float* selb  = (const float*)d_in[14];
  const float* ln2g  = (const float*)d_in[15];
  const float* ln2b  = (const float*)d_in[16];
  const float* sW1   = (const float*)d_in[17];
  const float* sb1   = (const float*)d_in[18];
  const float* sW2   = (const float*)d_in[19];
  const float* sb2   = (const float*)d_in[20];

  const int E = in_sizes[2];            // 400000
  const int G = in_sizes[1] / 256;      // 64

  char* ws = (char*)d_ws;
  __bf16* W1p   = (__bf16*)(ws);                 // 131072 B
  __bf16* W2p   = (__bf16*)(ws + 131072);        // 131072 B
  float*  C0    = (float*)(ws + 262144);
  float*  GW6   = (float*)(ws + 263168);
  float*  GW7   = (float*)(ws + 264192);
  float*  pooled= (float*)(ws + 265216);         // 65536 B
  float*  cnts  = (float*)(ws + 330752);         // 256 B
  int*    mflag = (int*)(ws + 331008);           // 4 B
  (void)ws_size; (void)n_in; (void)out_size;

  hipMemsetAsync(ws + 265216, 0, 65536 + 256, stream);  // pooled + counts

  prep_pack<<<64, 256, 0, stream>>>(W1, W2, ln1g, W1p, W2p);
  prep_vec<<<1, 1024, 0, stream>>>(W1, ln1g, ln1b, b1, (const unsigned*)smask,
                                   C0, GW6, GW7, mflag);
  edge_kernel<<<E / EPB, 256, 0, stream>>>(
      tok, ebatch, (const unsigned char*)smask, eheads, etails, curtail,
      W1p, W2p, C0, GW6, GW7, b2, selw, selb, mflag,
      (float*)d_out, pooled, cnts);
  stop_kernel<<<G, 256, 0, stream>>>(pooled, cnts, qtok, ln2g, ln2b,
                                     sW1, sb1, sW2, sb2,
                                     (float*)d_out + E, (float*)d_out + E + G);
}

// Round 9
// 300.461 us; speedup vs baseline: 5.0649x; 1.0604x over previous
//
#include <hip/hip_runtime.h>
#include <hip/hip_bf16.h>
#include <cstdint>

// EdgeFrontierPolicy: E=400000, G=64, H=256.
// r8 structure (318us): cooperative 64-edge block, A-tile in LDS (swizzled),
// B-frags streamed from L2 with reg double-buffer, 4 barriers/block.
// r9 delta: occupancy 2 -> 3 waves/SIMD via launch_bounds(256,3) (170-reg
// budget) + 2-pass LN (arch-reg peak 128 -> ~80, total ~150 incl. 64 acc).

typedef __bf16 bf16x8 __attribute__((ext_vector_type(8)));
typedef float  f32x4  __attribute__((ext_vector_type(4)));

__device__ __forceinline__ float gelu_f(float x) {
  float x2 = x * x;
  float t1 = __builtin_fmaf(0.1029444f, x2, 2.3022078f);
  float a  = x * t1;
  float e;
  asm("v_exp_f32 %0, %1" : "=v"(e) : "v"(a));
  float r;
  asm("v_rcp_f32 %0, %1" : "=v"(r) : "v"(e + 1.0f));
  return x - x * r;
}

__device__ __forceinline__ bf16x8 as_frag(uint4 u) {
  union { uint4 u; bf16x8 f; } c; c.u = u; return c.f;
}

// ---------------------------------------------------------------------------
// Pack W1 (ln1_g folded) / W2 into MFMA-B fragment order, bf16.
// frag(kt,nt) lane l: byte (kt*16+nt)*1024 + l*16.
__global__ void prep_pack(const float* __restrict__ W1, const float* __restrict__ W2,
                          const float* __restrict__ ln1g,
                          __bf16* __restrict__ W1p, __bf16* __restrict__ W2p) {
  int gid = blockIdx.x * blockDim.x + threadIdx.x;   // 16384 threads
  int m  = gid >> 13;
  int b  = (gid >> 6) & 127;
  int l  = gid & 63;
  int kt = b >> 4, nt = b & 15;
  int k0 = kt * 32 + ((l >> 4) << 3);
  int n  = nt * 16 + (l & 15);
  const float* W = m ? W2 : W1;
  bf16x8 v;
#pragma unroll
  for (int i = 0; i < 8; ++i) {
    int k = k0 + i;
    float wv = W[k * 256 + n];
    if (!m) wv *= ln1g[k];
    v[i] = (__bf16)wv;
  }
  __bf16* dst = m ? W2p : W1p;
  *(bf16x8*)(dst + (size_t)(b * 64 + l) * 8) = v;
}

// C0/GW6/GW7 + mask dtype detect.
__global__ void prep_vec(const float* __restrict__ W1, const float* __restrict__ ln1g,
                         const float* __restrict__ ln1b, const float* __restrict__ b1,
                         const unsigned* __restrict__ smask_words,
                         float* __restrict__ C0, float* __restrict__ GW6,
                         float* __restrict__ GW7, int* __restrict__ maskIsByte) {
  __shared__ float red[4][256];
  const int n = threadIdx.x & 255, c = threadIdx.x >> 8;
  const int k0 = c * 64, k1 = (c == 3) ? 258 : k0 + 64;
  float s = 0.f;
#pragma unroll 4
  for (int k = k0; k < k1; ++k) s += ln1b[k] * W1[k * 256 + n];
  red[c][n] = s;
  __syncthreads();
  if (c == 0) {
    C0[n]  = b1[n] + red[0][n] + red[1][n] + red[2][n] + red[3][n];
    GW6[n] = ln1g[256] * W1[256 * 256 + n];
    GW7[n] = ln1g[257] * W1[257 * 256 + n];
  }
  if (threadIdx.x == 0) {
    int big = 0;
    for (int i = 0; i < 64; ++i) { if (smask_words[i] > 1u) big = 1; }
    *maskIsByte = big;
  }
}

// ---------------------------------------------------------------------------
#define EPB 64

// 8 K-steps; B-frags from global (L2-hot, reg double-buffer); NO barriers.
__device__ __forceinline__ void gemm8_reg(const char* __restrict__ Wp,
                                          const char* aBase, unsigned swA,
                                          unsigned gA, int bOff,
                                          f32x4 (&acc)[4][4]) {
  uint4 bv[4], bn[4];
#pragma unroll
  for (int cf = 0; cf < 4; ++cf)
    bv[cf] = *(const uint4*)(Wp + bOff + (cf << 10));
#pragma unroll
  for (int kt = 0; kt < 8; ++kt) {
    if (kt < 7) {
#pragma unroll
      for (int cf = 0; cf < 4; ++cf)
        bn[cf] = *(const uint4*)(Wp + (kt + 1) * 16384 + bOff + (cf << 10));
    }
    bf16x8 av[4];
#pragma unroll
    for (int rf = 0; rf < 4; ++rf)
      av[rf] = *(const bf16x8*)(aBase + rf * 8192 + (((unsigned)(kt * 64) + gA) ^ swA));
#pragma unroll
    for (int rf = 0; rf < 4; ++rf)
#pragma unroll
      for (int cf = 0; cf < 4; ++cf)
        acc[rf][cf] = __builtin_amdgcn_mfma_f32_16x16x32_bf16(av[rf], as_frag(bv[cf]),
                                                              acc[rf][cf], 0, 0, 0);
#pragma unroll
    for (int cf = 0; cf < 4; ++cf) bv[cf] = bn[cf];
  }
}

__global__ __launch_bounds__(256, 3) void edge_kernel(
    const float* __restrict__ tok, const int* __restrict__ ebatch,
    const unsigned char* __restrict__ smaskB,
    const int* __restrict__ eheads, const int* __restrict__ etails,
    const int* __restrict__ curtail,
    const __bf16* __restrict__ W1p, const __bf16* __restrict__ W2p,
    const float* __restrict__ C0v, const float* __restrict__ GW6v,
    const float* __restrict__ GW7v, const float* __restrict__ b2v,
    const float* __restrict__ selwv, const float* __restrict__ selbv,
    const int* __restrict__ maskFlag,
    float* __restrict__ outLogits, float* __restrict__ pooledAcc,
    float* __restrict__ cnts) {
  __shared__ __align__(16) char As_[64 * 512];          // 32KB, XOR-swizzled rows
  __shared__ float sZa0[64], sZa1[64], sFront[64];
  __shared__ float sLog[64][4];
  __shared__ int sG[64];

  const int t = threadIdx.x;
  const int w = t >> 6, l = t & 63;
  const int base = blockIdx.x * EPB;

  // ---- flags ----
  if (t < 64) {
    int ge = base + t;
    int g  = ebatch[ge];
    int mb = *maskFlag;
    int mv = mb ? (int)smaskB[ge] : ((const int*)smaskB)[ge];
    int cand = (mv == 0);
    int cur  = curtail[g];
    int fr   = cand && ((eheads[ge] == cur) || (etails[ge] == cur));
    sZa0[t] = (float)cand; sZa1[t] = (float)fr; sFront[t] = (float)fr; sG[t] = g;
  }
  __syncthreads();

  if (t == 0) {  // counts: run-length over sorted graph ids (overlaps LN)
    int cg = sG[0]; float run = 1.f;
    for (int e = 1; e < EPB; ++e) {
      int g = sG[e];
      if (g == cg) run += 1.f;
      else { atomicAdd(&cnts[cg], run); cg = g; run = 1.f; }
    }
    atomicAdd(&cnts[cg], run);
  }

  // ---- LayerNorm over 258 (4 threads/edge), 2-pass, bf16 A tile, swizzled ----
  {
    const int e = t >> 2, q = t & 3;
    const float* rp = tok + (size_t)(base + e) * 256 + q * 4;
    // pass 1: stats only (no value storage -> low register pressure)
    float s = 0.f, s2 = 0.f;
#pragma unroll
    for (int j = 0; j < 16; ++j) {
      float4 v = *(const float4*)(rp + j * 16);
      s  += v.x + v.y + v.z + v.w;
      s2 += v.x * v.x + v.y * v.y + v.z * v.z + v.w * v.w;
    }
    float a0 = 0.f, a1 = 0.f;
    if (q == 0) { a0 = sZa0[e]; a1 = sZa1[e]; s += a0 + a1; s2 += a0 + a1; }
    s  += __shfl_xor(s, 1);  s  += __shfl_xor(s, 2);
    s2 += __shfl_xor(s2, 1); s2 += __shfl_xor(s2, 2);
    const float mean = s * (1.0f / 258.0f);
    const float var  = s2 * (1.0f / 258.0f) - mean * mean;
    const float rstd = rsqrtf(var + 1e-5f);
    const float nm   = -mean * rstd;
    const unsigned sw = (unsigned)(e & 7) << 4;
    // pass 2: reload (L2-hot; opaque ptr defeats CSE), convert, store
    const float* rp2 = rp;
    asm volatile("" : "+v"(rp2));
#pragma unroll
    for (int j = 0; j < 16; ++j) {
      float4 v = *(const float4*)(rp2 + j * 16);
      union { __bf16 h[4]; uint2 u; } cv;
      cv.h[0] = (__bf16)__builtin_fmaf(v.x, rstd, nm);
      cv.h[1] = (__bf16)__builtin_fmaf(v.y, rstd, nm);
      cv.h[2] = (__bf16)__builtin_fmaf(v.z, rstd, nm);
      cv.h[3] = (__bf16)__builtin_fmaf(v.w, rstd, nm);
      unsigned off = (unsigned)(q * 8 + j * 32);
      *(uint2*)(As_ + e * 512 + (off ^ sw)) = cv.u;
    }
    if (q == 0) {
      sZa0[e] = __builtin_fmaf(a0, rstd, nm);
      sZa1[e] = __builtin_fmaf(a1, rstd, nm);
    }
  }
  __syncthreads();   // barrier 1: A tile + normalized aux visible

  // ---- per-thread geometry + acc init (C0 + rank-2 aux) ----
  const int rA = l & 15;
  const int r0 = (l >> 4) << 2;
  f32x4 acc[4][4];
  {
    float c0r[4], w6r[4], w7r[4];
#pragma unroll
    for (int cf = 0; cf < 4; ++cf) {
      int col = w * 64 + cf * 16 + rA;
      c0r[cf] = C0v[col]; w6r[cf] = GW6v[col]; w7r[cf] = GW7v[col];
    }
    f32x4 za0q[4], za1q[4];
#pragma unroll
    for (int rf = 0; rf < 4; ++rf) {
      za0q[rf] = *(const f32x4*)&sZa0[rf * 16 + r0];
      za1q[rf] = *(const f32x4*)&sZa1[rf * 16 + r0];
    }
#pragma unroll
    for (int rf = 0; rf < 4; ++rf)
#pragma unroll
      for (int cf = 0; cf < 4; ++cf)
#pragma unroll
        for (int i = 0; i < 4; ++i)
          acc[rf][cf][i] = c0r[cf] + za0q[rf][i] * w6r[cf] + za1q[rf][i] * w7r[cf];
  }

  const unsigned swA = (unsigned)(rA & 7) << 4;
  const unsigned gA  = (unsigned)((l >> 4) << 4);
  const char* aBase  = As_ + rA * 512;
  const int bOff     = (w << 12) + (l << 4);

  // ---- GEMM1 (B from L2, no barriers) ----
  gemm8_reg((const char*)W1p, aBase, swA, gA, bOff, acc);
  __syncthreads();   // barrier 2: all GEMM1 A-reads complete

  // ---- epilogue 1: gelu -> bf16 back into A tile ----
#pragma unroll
  for (int rf = 0; rf < 4; ++rf)
#pragma unroll
    for (int i = 0; i < 4; ++i) {
      int row = rf * 16 + r0 + i;
      char* rowp = As_ + row * 512;
      unsigned sw = (unsigned)(row & 7) << 4;
#pragma unroll
      for (int cf = 0; cf < 4; ++cf) {
        int col = w * 64 + cf * 16 + rA;
        *(__bf16*)(rowp + (((unsigned)(col * 2)) ^ sw)) = (__bf16)gelu_f(acc[rf][cf][i]);
      }
    }
  __syncthreads();   // barrier 3: h1 visible

  // ---- GEMM2 ----
#pragma unroll
  for (int cf = 0; cf < 4; ++cf) {
    float bb = b2v[w * 64 + cf * 16 + rA];
#pragma unroll
    for (int rf = 0; rf < 4; ++rf)
#pragma unroll
      for (int i = 0; i < 4; ++i) acc[rf][cf][i] = bb;
  }
  gemm8_reg((const char*)W2p, aBase, swA, gA, bOff, acc);

  // ---- epilogue 2: gelu -> logits + pooled ----
#pragma unroll
  for (int rf = 0; rf < 4; ++rf)
#pragma unroll
    for (int cf = 0; cf < 4; ++cf)
#pragma unroll
      for (int i = 0; i < 4; ++i) acc[rf][cf][i] = gelu_f(acc[rf][cf][i]);

  {
    float lwr[4];
#pragma unroll
    for (int cf = 0; cf < 4; ++cf) lwr[cf] = selwv[w * 64 + cf * 16 + rA];
#pragma unroll
    for (int rf = 0; rf < 4; ++rf)
#pragma unroll
      for (int i = 0; i < 4; ++i) {
        float p = acc[rf][0][i] * lwr[0] + acc[rf][1][i] * lwr[1]
                + acc[rf][2][i] * lwr[2] + acc[rf][3][i] * lwr[3];
        p += __shfl_xor(p, 1); p += __shfl_xor(p, 2);
        p += __shfl_xor(p, 4); p += __shfl_xor(p, 8);
        if (rA == 0) sLog[rf * 16 + r0 + i][w] = p;
      }
  }
  __syncthreads();   // barrier 4: sLog complete
  if (t < 64)
    outLogits[base + t] = sLog[t][0] + sLog[t][1] + sLog[t][2] + sLog[t][3]
                        + selbv[0] + 0.5f * sFront[t];

  if (sG[0] == sG[EPB - 1]) {
    int g = sG[0];
#pragma unroll
    for (int cf = 0; cf < 4; ++cf) {
      float sv = 0.f;
#pragma unroll
      for (int rf = 0; rf < 4; ++rf)
#pragma unroll
        for (int i = 0; i < 4; ++i) sv += acc[rf][cf][i];
      sv += __shfl_xor(sv, 16);
      sv += __shfl_xor(sv, 32);
      if (l < 16) atomicAdd(&pooledAcc[g * 256 + w * 64 + cf * 16 + l], sv);
    }
  } else {  // graph-boundary block (rare)
#pragma unroll
    for (int rf = 0; rf < 4; ++rf)
#pragma unroll
      for (int i = 0; i < 4; ++i) {
        int row = rf * 16 + r0 + i;
        int g = sG[row];
#pragma unroll
        for (int cf = 0; cf < 4; ++cf)
          atomicAdd(&pooledAcc[g * 256 + w * 64 + cf * 16 + rA], acc[rf][cf][i]);
      }
  }
}

// ---------------------------------------------------------------------------
__global__ __launch_bounds__(256) void stop_kernel(
    const float* __restrict__ pooledAcc, const float* __restrict__ cnts,
    const float* __restrict__ qtok,
    const float* __restrict__ ln2g, const float* __restrict__ ln2b,
    const float* __restrict__ sW1, const float* __restrict__ sb1,
    const float* __restrict__ sW2, const float* __restrict__ sb2,
    float* __restrict__ outStop, float* __restrict__ outPooled) {
  __shared__ float sIn[512], sLn[512], sRed[8];
  const int t = threadIdx.x, g = blockIdx.x;
  const int w = t >> 6, l = t & 63;
  float c = fmaxf(cnts[g], 1.0f);
  float p = pooledAcc[g * 256 + t] / c;
  outPooled[g * 256 + t] = p;
  sIn[t] = p;
  sIn[256 + t] = qtok[g * 256 + t];
  __syncthreads();
  float a = sIn[t], b = sIn[256 + t];
  float s = a + b, s2 = a * a + b * b;
#pragma unroll
  for (int m = 1; m < 64; m <<= 1) { s += __shfl_xor(s, m); s2 += __shfl_xor(s2, m); }
  if (l == 0) { sRed[w] = s; sRed[4 + w] = s2; }
  __syncthreads();
  s  = sRed[0] + sRed[1] + sRed[2] + sRed[3];
  s2 = sRed[4] + sRed[5] + sRed[6] + sRed[7];
  const float mean = s * (1.0f / 512.0f);
  const float var  = s2 * (1.0f / 512.0f) - mean * mean;
  const float rstd = rsqrtf(var + 1e-5f);
  sLn[t]       = (a - mean) * rstd * ln2g[t] + ln2b[t];
  sLn[256 + t] = (b - mean) * rstd * ln2g[256 + t] + ln2b[256 + t];
  __syncthreads();
  float accv = sb1[t];
#pragma unroll 8
  for (int k = 0; k < 512; ++k) accv += sLn[k] * sW1[k * 256 + t];
  float u = gelu_f(accv);
  float part = u * sW2[t];
#pragma unroll
  for (int m = 1; m < 64; m <<= 1) part += __shfl_xor(part, m);
  if (l == 0) sRed[w] = part;
  __syncthreads();
  if (t == 0) outStop[g] = sRed[0] + sRed[1] + sRed[2] + sRed[3] + sb2[0];
}

// ---------------------------------------------------------------------------
extern "C" void kernel_launch(void* const* d_in, const int* in_sizes, int n_in,
                              void* d_out, int out_size, void* d_ws, size_t ws_size,
                              hipStream_t stream) {
  const float* tok   = (const float*)d_in[0];
  const float* qtok  = (const float*)d_in[1];
  const int* ebatch  = (const int*)d_in[2];
  const void* smask  = d_in[3];
  const int* eheads  = (const int*)d_in[4];
  const int* etails  = (const int*)d_in[5];
  const int* curtail = (const int*)d_in[6];
  const float* ln1g  = (const float*)d_in[7];
  const float* ln1b  = (const float*)d_in[8];
  const float* W1    = (const float*)d_in[9];
  const float* b1    = (const float*)d_in[10];
  const float* W2    = (const float*)d_in[11];
  const float* b2    = (const float*)d_in[12];
  const float* selw  = (const float*)d_in[13];
  const float* selb  = (const float*)d_in[14];
  const float* ln2g  = (const float*)d_in[15];
  const float* ln2b  = (const float*)d_in[16];
  const float* sW1   = (const float*)d_in[17];
  const float* sb1   = (const float*)d_in[18];
  const float* sW2   = (const float*)d_in[19];
  const float* sb2   = (const float*)d_in[20];

  const int E = in_sizes[2];            // 400000
  const int G = in_sizes[1] / 256;      // 64

  char* ws = (char*)d_ws;
  __bf16* W1p   = (__bf16*)(ws);                 // 131072 B
  __bf16* W2p   = (__bf16*)(ws + 131072);        // 131072 B
  float*  C0    = (float*)(ws + 262144);
  float*  GW6   = (float*)(ws + 263168);
  float*  GW7   = (float*)(ws + 264192);
  float*  pooled= (float*)(ws + 265216);         // 65536 B
  float*  cnts  = (float*)(ws + 330752);         // 256 B
  int*    mflag = (int*)(ws + 331008);           // 4 B
  (void)ws_size; (void)n_in; (void)out_size;

  hipMemsetAsync(ws + 265216, 0, 65536 + 256, stream);  // pooled + counts

  prep_pack<<<64, 256, 0, stream>>>(W1, W2, ln1g, W1p, W2p);
  prep_vec<<<1, 1024, 0, stream>>>(W1, ln1g, ln1b, b1, (const unsigned*)smask,
                                   C0, GW6, GW7, mflag);
  edge_kernel<<<E / EPB, 256, 0, stream>>>(
      tok, ebatch, (const unsigned char*)smask, eheads, etails, curtail,
      W1p, W2p, C0, GW6, GW7, b2, selw, selb, mflag,
      (float*)d_out, pooled, cnts);
  stop_kernel<<<G, 256, 0, stream>>>(pooled, cnts, qtok, ln2g, ln2b,
                                     sW1, sb1, sW2, sb2,
                                     (float*)d_out + E, (float*)d_out + E + G);
}